// Round 1
// baseline (563.635 us; speedup 1.0000x reference)
//
#include <hip/hip_runtime.h>
#include <stdint.h>

#define S_LEN 2048
#define DMODEL 1024
#define NHEAD 16
#define HDIM 64
#define NE 3072

typedef __attribute__((ext_vector_type(8))) short short8_t;
typedef __attribute__((ext_vector_type(4))) float f32x4;

__device__ __forceinline__ float bf2f(ushort u) {
  union { float f; uint32_t i; } c; c.i = ((uint32_t)u) << 16; return c.f;
}
__device__ __forceinline__ ushort f2bf(float f) {
  union { float f; uint32_t i; } c; c.f = f;
  uint32_t x = c.i;
  return (ushort)((x + 0x7fffu + ((x >> 16) & 1u)) >> 16);
}

__device__ __forceinline__ void gload_lds16(const ushort* g, ushort* l) {
  __builtin_amdgcn_global_load_lds(
      (const __attribute__((address_space(1))) void*)g,
      (__attribute__((address_space(3))) void*)l, 16, 0, 0);
}

// ---------------- fp32 -> bf16 convert ----------------
__global__ void cvt_f32_bf16(const float* __restrict__ in, ushort* __restrict__ out, int n4) {
  int i = blockIdx.x * blockDim.x + threadIdx.x;
  if (i < n4) {
    float4 v = ((const float4*)in)[i];
    ushort4 o;
    o.x = f2bf(v.x); o.y = f2bf(v.y); o.z = f2bf(v.z); o.w = f2bf(v.w);
    ((ushort4*)out)[i] = o;
  }
}

// ---------------- bf16 GEMM: C[M][N] = A[M][K] * B[N][K]^T ----------------
// 128x128 tile, BK=32, 4 waves (2x2), each wave 64x64 via 4x4 MFMA 16x16x32.
// Frag layout: A/B lane l -> row/col = l&15, k = 8*(l>>4) + j (contiguous 8).
// C/D: col = l&15, row = 4*(l>>4) + reg.
template<int OUT_BF16>
__global__ __launch_bounds__(256) void gemm_abt(
    const ushort* __restrict__ A, const ushort* __restrict__ B,
    void* __restrict__ Cv, int M, int N, int K)
{
  __shared__ ushort lds[8192];  // A tile [128][32] then B tile [128][32]
  const int nbn = N >> 7;
  const int bm = blockIdx.x / nbn;
  const int bn = blockIdx.x - bm * nbn;
  const int tid = threadIdx.x;
  const int w = tid >> 6, l = tid & 63;
  const int wm = w >> 1, wn = w & 1;
  const int fr = l & 15, fg = l >> 4;

  f32x4 acc[4][4];
#pragma unroll
  for (int r = 0; r < 4; ++r)
#pragma unroll
    for (int c = 0; c < 4; ++c) acc[r][c] = (f32x4){0.f, 0.f, 0.f, 0.f};

  // staging: wave w covers tile rows [w*32, w*32+31]; lane l -> row w*32 + (l>>2), col (l&3)*8
  const ushort* ga0 = A + (size_t)(bm * 128 + w * 32 + (l >> 2)) * K + (l & 3) * 8;
  const ushort* gb0 = B + (size_t)(bn * 128 + w * 32 + (l >> 2)) * K + (l & 3) * 8;
  ushort* la = &lds[w * 1024];
  ushort* lb = &lds[4096 + w * 1024];
  const ushort* fa = &lds[(wm * 64 + fr) * 32 + fg * 8];
  const ushort* fb = &lds[4096 + (wn * 64 + fr) * 32 + fg * 8];

  for (int k0 = 0; k0 < K; k0 += 32) {
    __syncthreads();
    gload_lds16(ga0 + k0, la);
    gload_lds16(ga0 + 16 * K + k0, la + 512);
    gload_lds16(gb0 + k0, lb);
    gload_lds16(gb0 + 16 * K + k0, lb + 512);
    __syncthreads();

    short8_t af[4], bf[4];
#pragma unroll
    for (int r = 0; r < 4; ++r) {
      union { short8_t v; uint4 q; } u;
      u.q = *(const uint4*)(fa + r * 512);
      af[r] = u.v;
    }
#pragma unroll
    for (int c = 0; c < 4; ++c) {
      union { short8_t v; uint4 q; } u;
      u.q = *(const uint4*)(fb + c * 512);
      bf[c] = u.v;
    }
#pragma unroll
    for (int r = 0; r < 4; ++r)
#pragma unroll
      for (int c = 0; c < 4; ++c)
        acc[r][c] = __builtin_amdgcn_mfma_f32_16x16x32_bf16(af[r], bf[c], acc[r][c], 0, 0, 0);
  }

  const int row0 = bm * 128 + wm * 64 + fg * 4;
  const int col0 = bn * 128 + wn * 64 + fr;
#pragma unroll
  for (int r = 0; r < 4; ++r)
#pragma unroll
    for (int c = 0; c < 4; ++c)
#pragma unroll
      for (int j = 0; j < 4; ++j) {
        int row = row0 + r * 16 + j;
        int col = col0 + c * 16;
        if (OUT_BF16)
          ((ushort*)Cv)[(size_t)row * N + col] = f2bf(acc[r][c][j]);
        else
          ((float*)Cv)[(size_t)row * N + col] = acc[r][c][j];
      }
}

// ---------------- RoPE in-place on Q and K sections of qkv ----------------
__global__ void rope_kernel(ushort* __restrict__ qkv) {
  int idx = blockIdx.x * blockDim.x + threadIdx.x;  // 2^21 threads
  int i = idx & 31;
  int hh = (idx >> 5) & (NHEAD - 1);
  int sec = (idx >> 9) & 1;
  int srow = idx >> 10;
  // inv_freq = 10000^(-i/32) = 2^(-i * log2(10000)/32)
  float invf = exp2f((float)i * (-13.287712379549449f / 32.f));
  float ang = (float)srow * invf;
  float sn, c;
  sincosf(ang, &sn, &c);
  size_t base = (size_t)srow * NE + (size_t)sec * DMODEL + hh * HDIM;
  float x1 = bf2f(qkv[base + i]);
  float x2 = bf2f(qkv[base + i + 32]);
  qkv[base + i]      = f2bf(x1 * c - x2 * sn);
  qkv[base + i + 32] = f2bf(x2 * c + x1 * sn);
}

// ---------------- flash attention (fp32 vector, causal) ----------------
#define QBLK 32
#define RW 8
#define TK 64
#define KST 66  // padded LDS stride: bank = (33*lane + d)%32 -> conflict-free

__global__ __launch_bounds__(256) void attn_fwd(
    const ushort* __restrict__ qkv, ushort* __restrict__ O,
    const int* __restrict__ icausal)
{
  const int h = blockIdx.x & (NHEAD - 1);
  const int rb = blockIdx.x >> 4;
  const int r0 = rb * QBLK;
  const int tid = threadIdx.x;
  const int w = tid >> 6, l = tid & 63;
  const int causal = *icausal;

  __shared__ ushort Klds[TK * KST];
  __shared__ ushort Vlds[TK * KST];
  __shared__ float qlds[QBLK][HDIM];
  __shared__ float plds[QBLK][TK];

  // load Q rows for this block (scaled by 1/sqrt(64))
  for (int i = tid; i < QBLK * HDIM; i += 256) {
    int rr = i >> 6, d = i & 63;
    qlds[rr][d] = bf2f(qkv[(size_t)(r0 + rr) * NE + h * HDIM + d]) * 0.125f;
  }

  float m[RW], sden[RW], o[RW], alpha[RW];
#pragma unroll
  for (int r = 0; r < RW; ++r) { m[r] = -1e30f; sden[r] = 0.f; o[r] = 0.f; }

  const int myrow0 = r0 + w * RW;
  const int kmax = causal ? (r0 + QBLK) : S_LEN;
  const int ntiles = (kmax + TK - 1) / TK;

  for (int t = 0; t < ntiles; ++t) {
    const int k0 = t * TK;
    __syncthreads();
    // stage K and V tiles [64 keys][64 d] with padded stride
    for (int c = tid; c < 512; c += 256) {
      int row = c >> 3, col8 = (c & 7) << 3;
      const ushort* src = qkv + (size_t)(k0 + row) * NE + DMODEL + h * HDIM + col8;
      uint4 kv4 = *(const uint4*)src;
      uint4 vv4 = *(const uint4*)(src + DMODEL);
      uint* dk = (uint*)&Klds[row * KST + col8];
      dk[0] = kv4.x; dk[1] = kv4.y; dk[2] = kv4.z; dk[3] = kv4.w;
      uint* dv = (uint*)&Vlds[row * KST + col8];
      dv[0] = vv4.x; dv[1] = vv4.y; dv[2] = vv4.z; dv[3] = vv4.w;
    }
    __syncthreads();

    // ---- phase 1: lane = key; K row hoisted to registers ----
    float kf[HDIM];
    {
      const uint* krow = (const uint*)&Klds[l * KST];
#pragma unroll
      for (int dd = 0; dd < 32; ++dd) {
        uint u = krow[dd];
        kf[2 * dd]     = bf2f((ushort)(u & 0xffffu));
        kf[2 * dd + 1] = bf2f((ushort)(u >> 16));
      }
    }
#pragma unroll
    for (int r = 0; r < RW; ++r) {
      const int row = myrow0 + r;
      float sc = 0.f;
      const float4* qp = (const float4*)&qlds[w * RW + r][0];
#pragma unroll
      for (int d4 = 0; d4 < 16; ++d4) {
        float4 q4 = qp[d4];
        sc = fmaf(q4.x, kf[4 * d4],     sc);
        sc = fmaf(q4.y, kf[4 * d4 + 1], sc);
        sc = fmaf(q4.z, kf[4 * d4 + 2], sc);
        sc = fmaf(q4.w, kf[4 * d4 + 3], sc);
      }
      if (causal && (k0 + l > row)) sc = -1e30f;
      if (!causal || k0 <= row) {
        float tm = sc;
#pragma unroll
        for (int off = 32; off; off >>= 1) tm = fmaxf(tm, __shfl_xor(tm, off));
        float mn = fmaxf(m[r], tm);
        float p = __expf(sc - mn);
        alpha[r] = __expf(m[r] - mn);
        float ps = p;
#pragma unroll
        for (int off = 32; off; off >>= 1) ps += __shfl_xor(ps, off);
        sden[r] = sden[r] * alpha[r] + ps;
        m[r] = mn;
        plds[w * RW + r][l] = p;
      } else {
        alpha[r] = 1.f;
        plds[w * RW + r][l] = 0.f;
      }
    }

    // ---- phase 2: lane = d; V column hoisted to registers ----
    float vf[TK];
#pragma unroll
    for (int k = 0; k < TK; ++k)
      vf[k] = bf2f(Vlds[k * KST + l]);
#pragma unroll
    for (int r = 0; r < RW; ++r) {
      float acc2 = 0.f;
      const float4* pp = (const float4*)&plds[w * RW + r][0];
#pragma unroll
      for (int k4 = 0; k4 < 16; ++k4) {
        float4 p4 = pp[k4];
        acc2 = fmaf(p4.x, vf[4 * k4],     acc2);
        acc2 = fmaf(p4.y, vf[4 * k4 + 1], acc2);
        acc2 = fmaf(p4.z, vf[4 * k4 + 2], acc2);
        acc2 = fmaf(p4.w, vf[4 * k4 + 3], acc2);
      }
      o[r] = o[r] * alpha[r] + acc2;
    }
  }

#pragma unroll
  for (int r = 0; r < RW; ++r) {
    int row = myrow0 + r;
    O[(size_t)row * DMODEL + h * HDIM + l] = f2bf(o[r] / sden[r]);
  }
}

// ---------------- launch ----------------
extern "C" void kernel_launch(void* const* d_in, const int* in_sizes, int n_in,
                              void* d_out, int out_size, void* d_ws, size_t ws_size,
                              hipStream_t stream) {
  const float* x     = (const float*)d_in[0];
  const float* w_in  = (const float*)d_in[1];
  const float* w_out = (const float*)d_in[2];
  const int* icausal = (const int*)d_in[3];

  char* ws = (char*)d_ws;
  ushort* xbf    = (ushort*)(ws);                  // 2048*1024
  ushort* winbf  = (ushort*)(ws + 4194304);        // 3072*1024
  ushort* woutbf = (ushort*)(ws + 10485760);       // 1024*1024
  ushort* qkv    = (ushort*)(ws + 12582912);       // 2048*3072
  ushort* obuf   = (ushort*)(ws + 25165824);       // 2048*1024

  cvt_f32_bf16<<<2048, 256, 0, stream>>>(x, xbf, 2097152 / 4);
  cvt_f32_bf16<<<3072, 256, 0, stream>>>(w_in, winbf, 3145728 / 4);
  cvt_f32_bf16<<<1024, 256, 0, stream>>>(w_out, woutbf, 1048576 / 4);

  gemm_abt<1><<<16 * 24, 256, 0, stream>>>(xbf, winbf, (void*)qkv, 2048, 3072, 1024);
  rope_kernel<<<8192, 256, 0, stream>>>(qkv);
  attn_fwd<<<16 * 64, 256, 0, stream>>>(qkv, obuf, icausal);
  gemm_abt<0><<<16 * 8, 256, 0, stream>>>(obuf, woutbf, d_out, 2048, 1024, 1024);
}

// Round 2
// 135.951 us; speedup vs baseline: 4.1459x; 4.1459x over previous
//
#include <hip/hip_runtime.h>
#include <stdint.h>

#define S_LEN 2048
#define DMODEL 1024
#define NHEAD 16
#define HDIM 64
#define NE 3072
#define C2 0.18033688011112042f  // 0.125 * log2(e)

typedef __attribute__((ext_vector_type(8))) short short8_t;
typedef __attribute__((ext_vector_type(4))) float f32x4;

__device__ __forceinline__ float bf2f(ushort u) {
  union { float f; uint32_t i; } c; c.i = ((uint32_t)u) << 16; return c.f;
}
__device__ __forceinline__ ushort f2bf(float f) {
  union { float f; uint32_t i; } c; c.f = f;
  uint32_t x = c.i;
  return (ushort)((x + 0x7fffu + ((x >> 16) & 1u)) >> 16);
}

__device__ __forceinline__ void gload_lds16(const ushort* g, ushort* l) {
  __builtin_amdgcn_global_load_lds(
      (const __attribute__((address_space(1))) void*)g,
      (__attribute__((address_space(3))) void*)l, 16, 0, 0);
}

// ---------------- fp32 -> bf16 convert ----------------
__global__ void cvt_f32_bf16(const float* __restrict__ in, ushort* __restrict__ out, int n4) {
  int i = blockIdx.x * blockDim.x + threadIdx.x;
  if (i < n4) {
    float4 v = ((const float4*)in)[i];
    ushort4 o;
    o.x = f2bf(v.x); o.y = f2bf(v.y); o.z = f2bf(v.z); o.w = f2bf(v.w);
    ((ushort4*)out)[i] = o;
  }
}

// ---------------- bf16 GEMM: C[M][N] = A[M][K] * B[N][K]^T ----------------
template<int OUT_BF16>
__global__ __launch_bounds__(256) void gemm_abt(
    const ushort* __restrict__ A, const ushort* __restrict__ B,
    void* __restrict__ Cv, int M, int N, int K)
{
  __shared__ ushort lds[8192];  // A tile [128][32] then B tile [128][32]
  const int nbn = N >> 7;
  const int bm = blockIdx.x / nbn;
  const int bn = blockIdx.x - bm * nbn;
  const int tid = threadIdx.x;
  const int w = tid >> 6, l = tid & 63;
  const int wm = w >> 1, wn = w & 1;
  const int fr = l & 15, fg = l >> 4;

  f32x4 acc[4][4];
#pragma unroll
  for (int r = 0; r < 4; ++r)
#pragma unroll
    for (int c = 0; c < 4; ++c) acc[r][c] = (f32x4){0.f, 0.f, 0.f, 0.f};

  const ushort* ga0 = A + (size_t)(bm * 128 + w * 32 + (l >> 2)) * K + (l & 3) * 8;
  const ushort* gb0 = B + (size_t)(bn * 128 + w * 32 + (l >> 2)) * K + (l & 3) * 8;
  ushort* la = &lds[w * 1024];
  ushort* lb = &lds[4096 + w * 1024];
  const ushort* fa = &lds[(wm * 64 + fr) * 32 + fg * 8];
  const ushort* fb = &lds[4096 + (wn * 64 + fr) * 32 + fg * 8];

  for (int k0 = 0; k0 < K; k0 += 32) {
    __syncthreads();
    gload_lds16(ga0 + k0, la);
    gload_lds16(ga0 + 16 * K + k0, la + 512);
    gload_lds16(gb0 + k0, lb);
    gload_lds16(gb0 + 16 * K + k0, lb + 512);
    __syncthreads();

    short8_t af[4], bfr[4];
#pragma unroll
    for (int r = 0; r < 4; ++r) {
      union { short8_t v; uint4 q; } u;
      u.q = *(const uint4*)(fa + r * 512);
      af[r] = u.v;
    }
#pragma unroll
    for (int c = 0; c < 4; ++c) {
      union { short8_t v; uint4 q; } u;
      u.q = *(const uint4*)(fb + c * 512);
      bfr[c] = u.v;
    }
#pragma unroll
    for (int r = 0; r < 4; ++r)
#pragma unroll
      for (int c = 0; c < 4; ++c)
        acc[r][c] = __builtin_amdgcn_mfma_f32_16x16x32_bf16(af[r], bfr[c], acc[r][c], 0, 0, 0);
  }

  const int row0 = bm * 128 + wm * 64 + fg * 4;
  const int col0 = bn * 128 + wn * 64 + fr;
#pragma unroll
  for (int r = 0; r < 4; ++r)
#pragma unroll
    for (int c = 0; c < 4; ++c)
#pragma unroll
      for (int j = 0; j < 4; ++j) {
        int row = row0 + r * 16 + j;
        int col = col0 + c * 16;
        if (OUT_BF16)
          ((ushort*)Cv)[(size_t)row * N + col] = f2bf(acc[r][c][j]);
        else
          ((float*)Cv)[(size_t)row * N + col] = acc[r][c][j];
      }
}

// ---------------- RoPE in-place on Q and K sections of qkv ----------------
__global__ void rope_kernel(ushort* __restrict__ qkv) {
  int idx = blockIdx.x * blockDim.x + threadIdx.x;  // 2^21 threads
  int i = idx & 31;
  int hh = (idx >> 5) & (NHEAD - 1);
  int sec = (idx >> 9) & 1;
  int srow = idx >> 10;
  float invf = exp2f((float)i * (-13.287712379549449f / 32.f));
  float ang = (float)srow * invf;
  float sn, c;
  sincosf(ang, &sn, &c);
  size_t base = (size_t)srow * NE + (size_t)sec * DMODEL + hh * HDIM;
  float x1 = bf2f(qkv[base + i]);
  float x2 = bf2f(qkv[base + i + 32]);
  qkv[base + i]      = f2bf(x1 * c - x2 * sn);
  qkv[base + i + 32] = f2bf(x2 * c + x1 * sn);
}

// ---------------- V transpose: qkv V-section -> vt[h][d][key] ----------------
__global__ __launch_bounds__(256) void transpose_v(
    const ushort* __restrict__ qkv, ushort* __restrict__ vt)
{
  __shared__ ushort t[64][72];
  const int h = blockIdx.x & 15, c = blockIdx.x >> 4;  // c: 64-key chunk
  const int tid = threadIdx.x;
#pragma unroll
  for (int j = 0; j < 2; ++j) {
    int idx = tid + 256 * j;
    int key = idx >> 3, d8 = (idx & 7) << 3;
    uint4 v = *(const uint4*)(qkv + (size_t)(c * 64 + key) * NE + 2 * DMODEL + h * HDIM + d8);
    *(uint4*)&t[key][d8] = v;
  }
  __syncthreads();
#pragma unroll
  for (int j = 0; j < 2; ++j) {
    int idx = tid + 256 * j;
    int d = idx >> 3, k8 = (idx & 7) << 3;
    ushort tmp[8];
#pragma unroll
    for (int i = 0; i < 8; ++i) tmp[i] = t[k8 + i][d];
    *(uint4*)(vt + (size_t)(h * 64 + d) * S_LEN + c * 64 + k8) = *(const uint4*)tmp;
  }
}

// ---------------- MFMA flash attention (causal) ----------------
// 1024 blocks = 16 heads x 64 row-blocks (rb = bid>>4 for causal load balance).
// 2 waves/block, 16 q-rows/wave. Swapped QK^T (S[key][q]) -> q lane-local;
// PV in O^T orientation (O[d][q]) -> alpha/den lane-local.
__global__ __launch_bounds__(128) void attn_mfma(
    const ushort* __restrict__ qkv, const ushort* __restrict__ vt,
    ushort* __restrict__ O, const int* __restrict__ icausal)
{
  __shared__ ushort Klds[64 * 64];
  __shared__ ushort Vlds[64 * 64];
  __shared__ __align__(16) ushort Plds[2][16 * 72];

  const int h  = blockIdx.x & 15;
  const int rb = blockIdx.x >> 4;     // 0..63, 32 q-rows each
  const int tid = threadIdx.x;
  const int w = tid >> 6;             // 0..1
  const int l = tid & 63;
  const int lq = l & 15, g = l >> 4;
  const int causal = *icausal;
  const int q0w = rb * 32 + w * 16;

  // Q B-fragments: lane holds Q[q0w+lq][dh*32 + 8g + j]
  short8_t qf[2];
  {
    const ushort* qp = qkv + (size_t)(q0w + lq) * NE + h * HDIM;
    union { short8_t v; uint4 q; } u0, u1;
    u0.q = *(const uint4*)(qp + 8 * g);
    u1.q = *(const uint4*)(qp + 32 + 8 * g);
    qf[0] = u0.v; qf[1] = u1.v;
  }

  float m_run = -1e30f, den = 0.f;
  f32x4 oacc[4];
#pragma unroll
  for (int i = 0; i < 4; ++i) oacc[i] = (f32x4){0.f, 0.f, 0.f, 0.f};

  const int nt = causal ? (rb / 2 + 1) : (S_LEN / 64);
  const int koff = DMODEL + h * HDIM;

  for (int t = 0; t < nt; ++t) {
    const int k0 = t * 64;
    __syncthreads();
    // stage K[64 keys][64 d] and Vt[64 d][64 keys], swizzled source (rule #21)
#pragma unroll
    for (int i = 0; i < 4; ++i) {
      int row = w * 32 + i * 8 + (l >> 3);
      int cb = (l & 7) ^ (row & 7);
      gload_lds16(qkv + (size_t)(k0 + row) * NE + koff + cb * 8, &Klds[(w * 32 + i * 8) * 64]);
      gload_lds16(vt + (size_t)(h * 64 + row) * S_LEN + k0 + cb * 8, &Vlds[(w * 32 + i * 8) * 64]);
    }
    __syncthreads();

    // QK^T: sacc[st] over d (2 halves of 32)
    f32x4 sacc[4];
#pragma unroll
    for (int st = 0; st < 4; ++st) sacc[st] = (f32x4){0.f, 0.f, 0.f, 0.f};
#pragma unroll
    for (int dh = 0; dh < 2; ++dh)
#pragma unroll
      for (int st = 0; st < 4; ++st) {
        int key = st * 16 + lq;
        int off = (key * 128 + (dh * 32 + 8 * g) * 2) ^ ((lq & 7) << 4);
        union { short8_t v; uint4 q; } u;
        u.q = *(const uint4*)((const char*)Klds + off);
        sacc[st] = __builtin_amdgcn_mfma_f32_16x16x32_bf16(u.v, qf[dh], sacc[st], 0, 0, 0);
      }

    // online softmax (q = lq is lane-local; keys spread over reg r and group g)
    float ss[16];
    float vmax = -1e30f;
    const bool domask = causal && (t == nt - 1);
#pragma unroll
    for (int st = 0; st < 4; ++st)
#pragma unroll
      for (int r = 0; r < 4; ++r) {
        float s = sacc[st][r];
        if (domask) {
          int keyg = k0 + st * 16 + 4 * g + r;
          if (keyg > q0w + lq) s = -1e30f;
        }
        ss[st * 4 + r] = s;
        vmax = fmaxf(vmax, s);
      }
    vmax = fmaxf(vmax, __shfl_xor(vmax, 16));
    vmax = fmaxf(vmax, __shfl_xor(vmax, 32));
    float mn = fmaxf(m_run, vmax);
    float alpha = exp2f((m_run - mn) * C2);
    m_run = mn;
    float mc2 = mn * C2;
    float psum = 0.f;
#pragma unroll
    for (int i = 0; i < 16; ++i) {
      float p = exp2f(fmaf(ss[i], C2, -mc2));
      psum += p;
      int key = (i >> 2) * 16 + 4 * g + (i & 3);
      Plds[w][lq * 72 + key] = f2bf(p);
    }
    psum += __shfl_xor(psum, 16);
    psum += __shfl_xor(psum, 32);
    den = den * alpha + psum;
#pragma unroll
    for (int i = 0; i < 4; ++i) {
      oacc[i][0] *= alpha; oacc[i][1] *= alpha;
      oacc[i][2] *= alpha; oacc[i][3] *= alpha;
    }

    // PV: O^T[d][q] += Vt_frag * P_frag^T
#pragma unroll
    for (int kk = 0; kk < 2; ++kk) {
      union { short8_t v; uint4 q; } pu;
      pu.q = *(const uint4*)&Plds[w][lq * 72 + kk * 32 + 8 * g];
#pragma unroll
      for (int dsub = 0; dsub < 4; ++dsub) {
        int d = dsub * 16 + lq;
        int off = (d * 128 + (kk * 32 + 8 * g) * 2) ^ ((lq & 7) << 4);
        union { short8_t v; uint4 q; } vu;
        vu.q = *(const uint4*)((const char*)Vlds + off);
        oacc[dsub] = __builtin_amdgcn_mfma_f32_16x16x32_bf16(vu.v, pu.v, oacc[dsub], 0, 0, 0);
      }
    }
  }

  // epilogue: normalize, bounce through wave-private Plds, coalesced store
  float inv = 1.f / den;
#pragma unroll
  for (int dsub = 0; dsub < 4; ++dsub)
#pragma unroll
    for (int r = 0; r < 4; ++r)
      Plds[w][lq * 72 + dsub * 16 + 4 * g + r] = f2bf(oacc[dsub][r] * inv);
#pragma unroll
  for (int j = 0; j < 2; ++j) {
    int idx = l + 64 * j;
    int q = idx >> 3, seg = idx & 7;
    uint4 val = *(const uint4*)&Plds[w][q * 72 + seg * 8];
    *(uint4*)(O + (size_t)(q0w + q) * DMODEL + h * HDIM + seg * 8) = val;
  }
}

// ---------------- launch ----------------
extern "C" void kernel_launch(void* const* d_in, const int* in_sizes, int n_in,
                              void* d_out, int out_size, void* d_ws, size_t ws_size,
                              hipStream_t stream) {
  const float* x     = (const float*)d_in[0];
  const float* w_in  = (const float*)d_in[1];
  const float* w_out = (const float*)d_in[2];
  const int* icausal = (const int*)d_in[3];

  char* ws = (char*)d_ws;
  ushort* xbf    = (ushort*)(ws);                  // 2048*1024 (dead after GEMM1)
  ushort* winbf  = (ushort*)(ws + 4194304);        // 3072*1024
  ushort* woutbf = (ushort*)(ws + 10485760);       // 1024*1024
  ushort* qkv    = (ushort*)(ws + 12582912);       // 2048*3072
  ushort* obuf   = (ushort*)(ws + 25165824);       // 2048*1024
  ushort* vt     = xbf;                            // reuse: 16*64*2048 = 4MB

  cvt_f32_bf16<<<2048, 256, 0, stream>>>(x, xbf, 2097152 / 4);
  cvt_f32_bf16<<<3072, 256, 0, stream>>>(w_in, winbf, 3145728 / 4);
  cvt_f32_bf16<<<1024, 256, 0, stream>>>(w_out, woutbf, 1048576 / 4);

  gemm_abt<1><<<16 * 24, 256, 0, stream>>>(xbf, winbf, (void*)qkv, 2048, 3072, 1024);
  rope_kernel<<<8192, 256, 0, stream>>>(qkv);
  transpose_v<<<512, 256, 0, stream>>>(qkv, vt);
  attn_mfma<<<1024, 128, 0, stream>>>(qkv, vt, obuf, icausal);
  gemm_abt<0><<<16 * 8, 256, 0, stream>>>(obuf, woutbf, d_out, 2048, 1024, 1024);
}

// Round 3
// 117.512 us; speedup vs baseline: 4.7964x; 1.1569x over previous
//
#include <hip/hip_runtime.h>
#include <stdint.h>

#define S_LEN 2048
#define DMODEL 1024
#define NHEAD 16
#define HDIM 64
#define NE 3072
#define C2 0.18033688011112042f  // 0.125 * log2(e)

typedef __attribute__((ext_vector_type(8))) short short8_t;
typedef __attribute__((ext_vector_type(4))) float f32x4;

__device__ __forceinline__ float bf2f(ushort u) {
  union { float f; uint32_t i; } c; c.i = ((uint32_t)u) << 16; return c.f;
}
__device__ __forceinline__ ushort f2bf(float f) {
  union { float f; uint32_t i; } c; c.f = f;
  uint32_t x = c.i;
  return (ushort)((x + 0x7fffu + ((x >> 16) & 1u)) >> 16);
}

__device__ __forceinline__ void gload_lds16(const ushort* g, ushort* l) {
  __builtin_amdgcn_global_load_lds(
      (const __attribute__((address_space(1))) void*)g,
      (__attribute__((address_space(3))) void*)l, 16, 0, 0);
}

// ---------------- fused fp32 -> bf16 convert (x, w_in, w_out) ----------------
__global__ void cvt_all(const float* __restrict__ x, const float* __restrict__ w_in,
                        const float* __restrict__ w_out,
                        ushort* __restrict__ xbf, ushort* __restrict__ winbf,
                        ushort* __restrict__ woutbf) {
  int i = blockIdx.x * blockDim.x + threadIdx.x;  // 1572864 float4s total
  const float* src; ushort* dst; int off;
  if (i < 524288)       { src = x;     dst = xbf;    off = i; }
  else if (i < 1310720) { src = w_in;  dst = winbf;  off = i - 524288; }
  else                  { src = w_out; dst = woutbf; off = i - 1310720; }
  float4 v = ((const float4*)src)[off];
  ushort4 o;
  o.x = f2bf(v.x); o.y = f2bf(v.y); o.z = f2bf(v.z); o.w = f2bf(v.w);
  ((ushort4*)dst)[off] = o;
}

// ---------------- bf16 GEMM: C[M][N] = A[M][K] * B[N][K]^T ----------------
// 4 waves (2x2). Wave output (BM/2)x(BN/2). BK=32. m97-lineage staging.
template<int BM, int BN, int OUT_BF16>
__global__ __launch_bounds__(256) void gemm_abt(
    const ushort* __restrict__ A, const ushort* __restrict__ B,
    void* __restrict__ Cv, int M, int N, int K)
{
  constexpr int AR = BM / 32;
  constexpr int AC = BN / 32;
  constexpr int NG = (BM + BN) / 16;  // 16-row gload chunks
  constexpr int PG = NG / 4;          // per wave
  __shared__ ushort lds[(BM + BN) * 32];

  const int nbn = N / BN;
  const int bm = blockIdx.x / nbn;
  const int bn = blockIdx.x - bm * nbn;
  const int tid = threadIdx.x;
  const int w = tid >> 6, l = tid & 63;
  const int wm = w >> 1, wn = w & 1;
  const int fr = l & 15, fg = l >> 4;

  f32x4 acc[AR][AC];
#pragma unroll
  for (int r = 0; r < AR; ++r)
#pragma unroll
    for (int c = 0; c < AC; ++c) acc[r][c] = (f32x4){0.f, 0.f, 0.f, 0.f};

  const ushort* gsrc[PG];
  ushort* ldst[PG];
#pragma unroll
  for (int i = 0; i < PG; ++i) {
    int c = w + 4 * i;
    if (c < BM / 16) {
      gsrc[i] = A + (size_t)(bm * BM + c * 16 + (l >> 2)) * K + (l & 3) * 8;
      ldst[i] = &lds[c * 512];
    } else {
      int c2 = c - BM / 16;
      gsrc[i] = B + (size_t)(bn * BN + c2 * 16 + (l >> 2)) * K + (l & 3) * 8;
      ldst[i] = &lds[BM * 32 + c2 * 512];
    }
  }

  const ushort* fa = &lds[(wm * (BM / 2) + fr) * 32 + fg * 8];
  const ushort* fb = &lds[BM * 32 + (wn * (BN / 2) + fr) * 32 + fg * 8];

  for (int k0 = 0; k0 < K; k0 += 32) {
    __syncthreads();
#pragma unroll
    for (int i = 0; i < PG; ++i) gload_lds16(gsrc[i] + k0, ldst[i]);
    __syncthreads();

    short8_t af[AR], bfr[AC];
#pragma unroll
    for (int r = 0; r < AR; ++r) {
      union { short8_t v; uint4 q; } u;
      u.q = *(const uint4*)(fa + r * 512);
      af[r] = u.v;
    }
#pragma unroll
    for (int c = 0; c < AC; ++c) {
      union { short8_t v; uint4 q; } u;
      u.q = *(const uint4*)(fb + c * 512);
      bfr[c] = u.v;
    }
    __builtin_amdgcn_s_setprio(1);
#pragma unroll
    for (int r = 0; r < AR; ++r)
#pragma unroll
      for (int c = 0; c < AC; ++c)
        acc[r][c] = __builtin_amdgcn_mfma_f32_16x16x32_bf16(af[r], bfr[c], acc[r][c], 0, 0, 0);
    __builtin_amdgcn_s_setprio(0);
  }

  const int row0 = bm * BM + wm * (BM / 2) + fg * 4;
  const int col0 = bn * BN + wn * (BN / 2) + fr;
#pragma unroll
  for (int r = 0; r < AR; ++r)
#pragma unroll
    for (int c = 0; c < AC; ++c)
#pragma unroll
      for (int j = 0; j < 4; ++j) {
        int row = row0 + r * 16 + j;
        int col = col0 + c * 16;
        if (OUT_BF16)
          ((ushort*)Cv)[(size_t)row * N + col] = f2bf(acc[r][c][j]);
        else
          ((float*)Cv)[(size_t)row * N + col] = acc[r][c][j];
      }
}

// ---------------- RoPE in-place on Q and K sections of qkv ----------------
__global__ void rope_kernel(ushort* __restrict__ qkv) {
  int idx = blockIdx.x * blockDim.x + threadIdx.x;  // 2^21 threads
  int i = idx & 31;
  int hh = (idx >> 5) & (NHEAD - 1);
  int sec = (idx >> 9) & 1;
  int srow = idx >> 10;
  float invf = exp2f((float)i * (-13.287712379549449f / 32.f));
  float ang = (float)srow * invf;
  float sn, c;
  sincosf(ang, &sn, &c);
  size_t base = (size_t)srow * NE + (size_t)sec * DMODEL + hh * HDIM;
  float x1 = bf2f(qkv[base + i]);
  float x2 = bf2f(qkv[base + i + 32]);
  qkv[base + i]      = f2bf(x1 * c - x2 * sn);
  qkv[base + i + 32] = f2bf(x2 * c + x1 * sn);
}

// ---------------- V transpose: qkv V-section -> vt[h][d][key] ----------------
__global__ __launch_bounds__(256) void transpose_v(
    const ushort* __restrict__ qkv, ushort* __restrict__ vt)
{
  __shared__ ushort t[64][72];
  const int h = blockIdx.x & 15, c = blockIdx.x >> 4;
  const int tid = threadIdx.x;
#pragma unroll
  for (int j = 0; j < 2; ++j) {
    int idx = tid + 256 * j;
    int key = idx >> 3, d8 = (idx & 7) << 3;
    uint4 v = *(const uint4*)(qkv + (size_t)(c * 64 + key) * NE + 2 * DMODEL + h * HDIM + d8);
    *(uint4*)&t[key][d8] = v;
  }
  __syncthreads();
#pragma unroll
  for (int j = 0; j < 2; ++j) {
    int idx = tid + 256 * j;
    int d = idx >> 3, k8 = (idx & 7) << 3;
    ushort tmp[8];
#pragma unroll
    for (int i = 0; i < 8; ++i) tmp[i] = t[k8 + i][d];
    *(uint4*)(vt + (size_t)(h * 64 + d) * S_LEN + c * 64 + k8) = *(const uint4*)tmp;
  }
}

// ---------------- MFMA flash attention (causal), double-buffered ----------------
__global__ __launch_bounds__(128) void attn_mfma(
    const ushort* __restrict__ qkv, const ushort* __restrict__ vt,
    ushort* __restrict__ O, const int* __restrict__ icausal)
{
  __shared__ ushort Klds[2][64 * 64];
  __shared__ ushort Vlds[2][64 * 64];
  __shared__ __align__(16) ushort Plds[2][16 * 72];

  const int h  = blockIdx.x & 15;
  const int rb = blockIdx.x >> 4;     // 0..63, 32 q-rows each
  const int tid = threadIdx.x;
  const int w = tid >> 6;             // 0..1
  const int l = tid & 63;
  const int lq = l & 15, g = l >> 4;
  const int causal = *icausal;
  const int q0w = rb * 32 + w * 16;

  short8_t qf[2];
  {
    const ushort* qp = qkv + (size_t)(q0w + lq) * NE + h * HDIM;
    union { short8_t v; uint4 q; } u0, u1;
    u0.q = *(const uint4*)(qp + 8 * g);
    u1.q = *(const uint4*)(qp + 32 + 8 * g);
    qf[0] = u0.v; qf[1] = u1.v;
  }

  float m_run = -1e30f, den = 0.f;
  f32x4 oacc[4];
#pragma unroll
  for (int i = 0; i < 4; ++i) oacc[i] = (f32x4){0.f, 0.f, 0.f, 0.f};

  const int nt = causal ? (rb / 2 + 1) : (S_LEN / 64);
  const int koff = DMODEL + h * HDIM;

  auto stage = [&](int t, int b) {
    const int k0 = t * 64;
#pragma unroll
    for (int i = 0; i < 4; ++i) {
      int row = w * 32 + i * 8 + (l >> 3);
      int cb = (l & 7) ^ (row & 7);
      gload_lds16(qkv + (size_t)(k0 + row) * NE + koff + cb * 8, &Klds[b][(w * 32 + i * 8) * 64]);
      gload_lds16(vt + (size_t)(h * 64 + row) * S_LEN + k0 + cb * 8, &Vlds[b][(w * 32 + i * 8) * 64]);
    }
  };

  stage(0, 0);
  __syncthreads();
  int buf = 0;

  for (int t = 0; t < nt; ++t) {
    const int k0 = t * 64;
    if (t + 1 < nt) stage(t + 1, buf ^ 1);  // issue early; hides under compute

    // QK^T: sacc[st] over d (2 halves of 32)
    f32x4 sacc[4];
#pragma unroll
    for (int st = 0; st < 4; ++st) sacc[st] = (f32x4){0.f, 0.f, 0.f, 0.f};
    __builtin_amdgcn_s_setprio(1);
#pragma unroll
    for (int dh = 0; dh < 2; ++dh)
#pragma unroll
      for (int st = 0; st < 4; ++st) {
        int key = st * 16 + lq;
        int off = (key * 128 + (dh * 32 + 8 * g) * 2) ^ ((lq & 7) << 4);
        union { short8_t v; uint4 q; } u;
        u.q = *(const uint4*)((const char*)Klds[buf] + off);
        sacc[st] = __builtin_amdgcn_mfma_f32_16x16x32_bf16(u.v, qf[dh], sacc[st], 0, 0, 0);
      }
    __builtin_amdgcn_s_setprio(0);

    // online softmax (q = lq lane-local; keys over reg r and group g)
    float ss[16];
    float vmax = -1e30f;
    const bool domask = causal && (t == nt - 1);
#pragma unroll
    for (int st = 0; st < 4; ++st)
#pragma unroll
      for (int r = 0; r < 4; ++r) {
        float s = sacc[st][r];
        if (domask) {
          int keyg = k0 + st * 16 + 4 * g + r;
          if (keyg > q0w + lq) s = -1e30f;
        }
        ss[st * 4 + r] = s;
        vmax = fmaxf(vmax, s);
      }
    vmax = fmaxf(vmax, __shfl_xor(vmax, 16));
    vmax = fmaxf(vmax, __shfl_xor(vmax, 32));
    float mn = fmaxf(m_run, vmax);
    float alpha = exp2f((m_run - mn) * C2);
    m_run = mn;
    float mc2 = mn * C2;
    float psum = 0.f;
    float pv[16];
#pragma unroll
    for (int i = 0; i < 16; ++i) {
      pv[i] = exp2f(fmaf(ss[i], C2, -mc2));
      psum += pv[i];
    }
    // pack P to bf16 pairs (keys st*16+4g+{0..3}) and write as b64
#pragma unroll
    for (int st = 0; st < 4; ++st) {
      uint d0, d1;
      asm("v_cvt_pk_bf16_f32 %0, %1, %2" : "=v"(d0) : "v"(pv[st * 4 + 0]), "v"(pv[st * 4 + 1]));
      asm("v_cvt_pk_bf16_f32 %0, %1, %2" : "=v"(d1) : "v"(pv[st * 4 + 2]), "v"(pv[st * 4 + 3]));
      uint2 dd; dd.x = d0; dd.y = d1;
      *(uint2*)&Plds[w][lq * 72 + st * 16 + 4 * g] = dd;
    }
    psum += __shfl_xor(psum, 16);
    psum += __shfl_xor(psum, 32);
    den = den * alpha + psum;
#pragma unroll
    for (int i = 0; i < 4; ++i) {
      oacc[i][0] *= alpha; oacc[i][1] *= alpha;
      oacc[i][2] *= alpha; oacc[i][3] *= alpha;
    }

    // PV: O^T[d][q] += Vt_frag * P_frag^T
    __builtin_amdgcn_s_setprio(1);
#pragma unroll
    for (int kk = 0; kk < 2; ++kk) {
      union { short8_t v; uint4 q; } pu;
      pu.q = *(const uint4*)&Plds[w][lq * 72 + kk * 32 + 8 * g];
#pragma unroll
      for (int dsub = 0; dsub < 4; ++dsub) {
        int d = dsub * 16 + lq;
        int off = (d * 128 + (kk * 32 + 8 * g) * 2) ^ ((lq & 7) << 4);
        union { short8_t v; uint4 q; } vu;
        vu.q = *(const uint4*)((const char*)Vlds[buf] + off);
        oacc[dsub] = __builtin_amdgcn_mfma_f32_16x16x32_bf16(vu.v, pu.v, oacc[dsub], 0, 0, 0);
      }
    }
    __builtin_amdgcn_s_setprio(0);

    __syncthreads();  // drains vmcnt(0): next buffer staged & visible
    buf ^= 1;
  }

  // epilogue: normalize, bounce through wave-private Plds, coalesced store
  float inv = 1.f / den;
#pragma unroll
  for (int dsub = 0; dsub < 4; ++dsub)
#pragma unroll
    for (int r = 0; r < 4; ++r)
      Plds[w][lq * 72 + dsub * 16 + 4 * g + r] = f2bf(oacc[dsub][r] * inv);
#pragma unroll
  for (int j = 0; j < 2; ++j) {
    int idx = l + 64 * j;
    int q = idx >> 3, seg = idx & 7;
    uint4 val = *(const uint4*)&Plds[w][q * 72 + seg * 8];
    *(uint4*)(O + (size_t)(q0w + q) * DMODEL + h * HDIM + seg * 8) = val;
  }
}

// ---------------- launch ----------------
extern "C" void kernel_launch(void* const* d_in, const int* in_sizes, int n_in,
                              void* d_out, int out_size, void* d_ws, size_t ws_size,
                              hipStream_t stream) {
  const float* x     = (const float*)d_in[0];
  const float* w_in  = (const float*)d_in[1];
  const float* w_out = (const float*)d_in[2];
  const int* icausal = (const int*)d_in[3];

  char* ws = (char*)d_ws;
  ushort* xbf    = (ushort*)(ws);                  // 2048*1024 (dead after GEMM1)
  ushort* winbf  = (ushort*)(ws + 4194304);        // 3072*1024
  ushort* woutbf = (ushort*)(ws + 10485760);       // 1024*1024
  ushort* qkv    = (ushort*)(ws + 12582912);       // 2048*3072
  ushort* obuf   = (ushort*)(ws + 25165824);       // 2048*1024
  ushort* vt     = xbf;                            // reuse: 16*64*2048 = 4MB

  cvt_all<<<6144, 256, 0, stream>>>(x, w_in, w_out, xbf, winbf, woutbf);

  gemm_abt<128, 64, 1><<<16 * 48, 256, 0, stream>>>(xbf, winbf, (void*)qkv, 2048, 3072, 1024);
  rope_kernel<<<8192, 256, 0, stream>>>(qkv);
  transpose_v<<<512, 256, 0, stream>>>(qkv, vt);
  attn_mfma<<<1024, 128, 0, stream>>>(qkv, vt, obuf, icausal);
  gemm_abt<64, 64, 0><<<32 * 16, 256, 0, stream>>>(obuf, woutbf, d_out, 2048, 1024, 1024);
}

// Round 4
// 110.701 us; speedup vs baseline: 5.0915x; 1.0615x over previous
//
#include <hip/hip_runtime.h>
#include <stdint.h>

#define S_LEN 2048
#define DMODEL 1024
#define NHEAD 16
#define HDIM 64
#define NE 3072
#define C2 0.18033688011112042f  // 0.125 * log2(e)

typedef __attribute__((ext_vector_type(8))) short short8_t;
typedef __attribute__((ext_vector_type(4))) float f32x4;

__device__ __forceinline__ float bf2f(ushort u) {
  union { float f; uint32_t i; } c; c.i = ((uint32_t)u) << 16; return c.f;
}
__device__ __forceinline__ ushort f2bf(float f) {
  union { float f; uint32_t i; } c; c.f = f;
  uint32_t x = c.i;
  return (ushort)((x + 0x7fffu + ((x >> 16) & 1u)) >> 16);
}

__device__ __forceinline__ void gload_lds16(const ushort* g, ushort* l) {
  __builtin_amdgcn_global_load_lds(
      (const __attribute__((address_space(1))) void*)g,
      (__attribute__((address_space(3))) void*)l, 16, 0, 0);
}

// ---------------- fused fp32 -> bf16 convert (x, w_in, w_out) ----------------
__global__ void cvt_all(const float* __restrict__ x, const float* __restrict__ w_in,
                        const float* __restrict__ w_out,
                        ushort* __restrict__ xbf, ushort* __restrict__ winbf,
                        ushort* __restrict__ woutbf) {
  int i = blockIdx.x * blockDim.x + threadIdx.x;  // 1572864 float4s total
  const float* src; ushort* dst; int off;
  if (i < 524288)       { src = x;     dst = xbf;    off = i; }
  else if (i < 1310720) { src = w_in;  dst = winbf;  off = i - 524288; }
  else                  { src = w_out; dst = woutbf; off = i - 1310720; }
  float4 v = ((const float4*)src)[off];
  ushort4 o;
  o.x = f2bf(v.x); o.y = f2bf(v.y); o.z = f2bf(v.z); o.w = f2bf(v.w);
  ((ushort4*)dst)[off] = o;
}

// ---------------- bf16 GEMM: C[M][N] = A[M][K] * B[N][K]^T ----------------
template<int BM, int BN, int OUT_BF16>
__global__ __launch_bounds__(256) void gemm_abt(
    const ushort* __restrict__ A, const ushort* __restrict__ B,
    void* __restrict__ Cv, int M, int N, int K)
{
  constexpr int AR = BM / 32;
  constexpr int AC = BN / 32;
  constexpr int NG = (BM + BN) / 16;
  constexpr int PG = NG / 4;
  __shared__ ushort lds[(BM + BN) * 32];

  const int nbn = N / BN;
  const int bm = blockIdx.x / nbn;
  const int bn = blockIdx.x - bm * nbn;
  const int tid = threadIdx.x;
  const int w = tid >> 6, l = tid & 63;
  const int wm = w >> 1, wn = w & 1;
  const int fr = l & 15, fg = l >> 4;

  f32x4 acc[AR][AC];
#pragma unroll
  for (int r = 0; r < AR; ++r)
#pragma unroll
    for (int c = 0; c < AC; ++c) acc[r][c] = (f32x4){0.f, 0.f, 0.f, 0.f};

  const ushort* gsrc[PG];
  ushort* ldst[PG];
#pragma unroll
  for (int i = 0; i < PG; ++i) {
    int c = w + 4 * i;
    if (c < BM / 16) {
      gsrc[i] = A + (size_t)(bm * BM + c * 16 + (l >> 2)) * K + (l & 3) * 8;
      ldst[i] = &lds[c * 512];
    } else {
      int c2 = c - BM / 16;
      gsrc[i] = B + (size_t)(bn * BN + c2 * 16 + (l >> 2)) * K + (l & 3) * 8;
      ldst[i] = &lds[BM * 32 + c2 * 512];
    }
  }

  const ushort* fa = &lds[(wm * (BM / 2) + fr) * 32 + fg * 8];
  const ushort* fb = &lds[BM * 32 + (wn * (BN / 2) + fr) * 32 + fg * 8];

  for (int k0 = 0; k0 < K; k0 += 32) {
    __syncthreads();
#pragma unroll
    for (int i = 0; i < PG; ++i) gload_lds16(gsrc[i] + k0, ldst[i]);
    __syncthreads();

    short8_t af[AR], bfr[AC];
#pragma unroll
    for (int r = 0; r < AR; ++r) {
      union { short8_t v; uint4 q; } u;
      u.q = *(const uint4*)(fa + r * 512);
      af[r] = u.v;
    }
#pragma unroll
    for (int c = 0; c < AC; ++c) {
      union { short8_t v; uint4 q; } u;
      u.q = *(const uint4*)(fb + c * 512);
      bfr[c] = u.v;
    }
    __builtin_amdgcn_s_setprio(1);
#pragma unroll
    for (int r = 0; r < AR; ++r)
#pragma unroll
      for (int c = 0; c < AC; ++c)
        acc[r][c] = __builtin_amdgcn_mfma_f32_16x16x32_bf16(af[r], bfr[c], acc[r][c], 0, 0, 0);
    __builtin_amdgcn_s_setprio(0);
  }

  const int row0 = bm * BM + wm * (BM / 2) + fg * 4;
  const int col0 = bn * BN + wn * (BN / 2) + fr;
#pragma unroll
  for (int r = 0; r < AR; ++r)
#pragma unroll
    for (int c = 0; c < AC; ++c)
#pragma unroll
      for (int j = 0; j < 4; ++j) {
        int row = row0 + r * 16 + j;
        int col = col0 + c * 16;
        if (OUT_BF16)
          ((ushort*)Cv)[(size_t)row * N + col] = f2bf(acc[r][c][j]);
        else
          ((float*)Cv)[(size_t)row * N + col] = acc[r][c][j];
      }
}

// ---------------- RoPE in-place on Q and K sections of qkv ----------------
__global__ void rope_kernel(ushort* __restrict__ qkv) {
  int idx = blockIdx.x * blockDim.x + threadIdx.x;
  int i = idx & 31;
  int hh = (idx >> 5) & (NHEAD - 1);
  int sec = (idx >> 9) & 1;
  int srow = idx >> 10;
  float invf = exp2f((float)i * (-13.287712379549449f / 32.f));
  float ang = (float)srow * invf;
  float sn, c;
  sincosf(ang, &sn, &c);
  size_t base = (size_t)srow * NE + (size_t)sec * DMODEL + hh * HDIM;
  float x1 = bf2f(qkv[base + i]);
  float x2 = bf2f(qkv[base + i + 32]);
  qkv[base + i]      = f2bf(x1 * c - x2 * sn);
  qkv[base + i + 32] = f2bf(x2 * c + x1 * sn);
}

// ---------------- V transpose: qkv V-section -> vt[h][d][key] ----------------
__global__ __launch_bounds__(256) void transpose_v(
    const ushort* __restrict__ qkv, ushort* __restrict__ vt)
{
  __shared__ ushort t[64][72];
  const int h = blockIdx.x & 15, c = blockIdx.x >> 4;
  const int tid = threadIdx.x;
#pragma unroll
  for (int j = 0; j < 2; ++j) {
    int idx = tid + 256 * j;
    int key = idx >> 3, d8 = (idx & 7) << 3;
    uint4 v = *(const uint4*)(qkv + (size_t)(c * 64 + key) * NE + 2 * DMODEL + h * HDIM + d8);
    *(uint4*)&t[key][d8] = v;
  }
  __syncthreads();
#pragma unroll
  for (int j = 0; j < 2; ++j) {
    int idx = tid + 256 * j;
    int d = idx >> 3, k8 = (idx & 7) << 3;
    ushort tmp[8];
#pragma unroll
    for (int i = 0; i < 8; ++i) tmp[i] = t[k8 + i][d];
    *(uint4*)(vt + (size_t)(h * 64 + d) * S_LEN + c * 64 + k8) = *(const uint4*)tmp;
  }
}

// ---------------- MFMA flash attention, key-split for load balance ----------------
// 1536 blocks = 16 heads x 96 items. Items (longest-first by dispatch order):
//   i in [0,64):  rb = 63-(i>>1), key-slice (i&1) of the tile range -> partials
//   i in [64,96): rb = 95-i (31..0), full range -> direct output
__global__ __launch_bounds__(128) void attn_mfma(
    const ushort* __restrict__ qkv, const ushort* __restrict__ vt,
    ushort* __restrict__ O, ushort* __restrict__ po, float2* __restrict__ pmd,
    const int* __restrict__ icausal)
{
  __shared__ ushort Klds[2][64 * 64];
  __shared__ ushort Vlds[2][64 * 64];
  __shared__ __align__(16) ushort Plds[2][16 * 72];

  const int h  = blockIdx.x & 15;
  const int i  = blockIdx.x >> 4;     // 0..95
  const int tid = threadIdx.x;
  const int w = tid >> 6;
  const int l = tid & 63;
  const int lq = l & 15, g = l >> 4;
  const int causal = *icausal;

  int rb, t0, t1, split, slice = 0, ntf;
  if (i < 64) {
    rb = 63 - (i >> 1);
    ntf = causal ? (rb / 2 + 1) : (S_LEN / 64);
    int half = ntf >> 1;
    slice = i & 1;
    split = 1;
    if (slice) { t0 = ntf - half; t1 = ntf; }
    else       { t0 = 0;          t1 = ntf - half; }
  } else {
    rb = 95 - i;
    ntf = causal ? (rb / 2 + 1) : (S_LEN / 64);
    t0 = 0; t1 = ntf; split = 0;
  }
  const int q0w = rb * 32 + w * 16;

  short8_t qf[2];
  {
    const ushort* qp = qkv + (size_t)(q0w + lq) * NE + h * HDIM;
    union { short8_t v; uint4 q; } u0, u1;
    u0.q = *(const uint4*)(qp + 8 * g);
    u1.q = *(const uint4*)(qp + 32 + 8 * g);
    qf[0] = u0.v; qf[1] = u1.v;
  }

  float m_run = -1e30f, den = 0.f;
  f32x4 oacc[4];
#pragma unroll
  for (int j = 0; j < 4; ++j) oacc[j] = (f32x4){0.f, 0.f, 0.f, 0.f};

  const int koff = DMODEL + h * HDIM;

  auto stage = [&](int t, int b) {
    const int k0 = t * 64;
#pragma unroll
    for (int ii = 0; ii < 4; ++ii) {
      int row = w * 32 + ii * 8 + (l >> 3);
      int cb = (l & 7) ^ (row & 7);
      gload_lds16(qkv + (size_t)(k0 + row) * NE + koff + cb * 8, &Klds[b][(w * 32 + ii * 8) * 64]);
      gload_lds16(vt + (size_t)(h * 64 + row) * S_LEN + k0 + cb * 8, &Vlds[b][(w * 32 + ii * 8) * 64]);
    }
  };

  stage(t0, 0);
  __syncthreads();
  int buf = 0;

  for (int t = t0; t < t1; ++t) {
    const int k0 = t * 64;
    if (t + 1 < t1) stage(t + 1, buf ^ 1);

    f32x4 sacc[4];
#pragma unroll
    for (int st = 0; st < 4; ++st) sacc[st] = (f32x4){0.f, 0.f, 0.f, 0.f};
    __builtin_amdgcn_s_setprio(1);
#pragma unroll
    for (int dh = 0; dh < 2; ++dh)
#pragma unroll
      for (int st = 0; st < 4; ++st) {
        int key = st * 16 + lq;
        int off = (key * 128 + (dh * 32 + 8 * g) * 2) ^ ((lq & 7) << 4);
        union { short8_t v; uint4 q; } u;
        u.q = *(const uint4*)((const char*)Klds[buf] + off);
        sacc[st] = __builtin_amdgcn_mfma_f32_16x16x32_bf16(u.v, qf[dh], sacc[st], 0, 0, 0);
      }
    __builtin_amdgcn_s_setprio(0);

    float ss[16];
    float vmax = -1e30f;
    const bool domask = causal && (t == ntf - 1);
#pragma unroll
    for (int st = 0; st < 4; ++st)
#pragma unroll
      for (int r = 0; r < 4; ++r) {
        float s = sacc[st][r];
        if (domask) {
          int keyg = k0 + st * 16 + 4 * g + r;
          if (keyg > q0w + lq) s = -1e30f;
        }
        ss[st * 4 + r] = s;
        vmax = fmaxf(vmax, s);
      }
    vmax = fmaxf(vmax, __shfl_xor(vmax, 16));
    vmax = fmaxf(vmax, __shfl_xor(vmax, 32));
    float mn = fmaxf(m_run, vmax);
    float alpha = exp2f((m_run - mn) * C2);
    m_run = mn;
    float mc2 = mn * C2;
    float psum = 0.f;
    float pvv[16];
#pragma unroll
    for (int j = 0; j < 16; ++j) {
      pvv[j] = exp2f(fmaf(ss[j], C2, -mc2));
      psum += pvv[j];
    }
#pragma unroll
    for (int st = 0; st < 4; ++st) {
      uint d0, d1;
      asm("v_cvt_pk_bf16_f32 %0, %1, %2" : "=v"(d0) : "v"(pvv[st * 4 + 0]), "v"(pvv[st * 4 + 1]));
      asm("v_cvt_pk_bf16_f32 %0, %1, %2" : "=v"(d1) : "v"(pvv[st * 4 + 2]), "v"(pvv[st * 4 + 3]));
      uint2 dd; dd.x = d0; dd.y = d1;
      *(uint2*)&Plds[w][lq * 72 + st * 16 + 4 * g] = dd;
    }
    psum += __shfl_xor(psum, 16);
    psum += __shfl_xor(psum, 32);
    den = den * alpha + psum;
#pragma unroll
    for (int j = 0; j < 4; ++j) {
      oacc[j][0] *= alpha; oacc[j][1] *= alpha;
      oacc[j][2] *= alpha; oacc[j][3] *= alpha;
    }

    __builtin_amdgcn_s_setprio(1);
#pragma unroll
    for (int kk = 0; kk < 2; ++kk) {
      union { short8_t v; uint4 q; } pu;
      pu.q = *(const uint4*)&Plds[w][lq * 72 + kk * 32 + 8 * g];
#pragma unroll
      for (int dsub = 0; dsub < 4; ++dsub) {
        int d = dsub * 16 + lq;
        int off = (d * 128 + (kk * 32 + 8 * g) * 2) ^ ((lq & 7) << 4);
        union { short8_t v; uint4 q; } vu;
        vu.q = *(const uint4*)((const char*)Vlds[buf] + off);
        oacc[dsub] = __builtin_amdgcn_mfma_f32_16x16x32_bf16(vu.v, pu.v, oacc[dsub], 0, 0, 0);
      }
    }
    __builtin_amdgcn_s_setprio(0);

    __syncthreads();
    buf ^= 1;
  }

  if (split) {
    // store unnormalized partial: po[h][j][qi][d] bf16, pmd[h][j][qi] = {m, den}
    const int j = (rb - 32) * 2 + slice;
    const int qi = w * 16 + lq;
    ushort* base = po + ((size_t)(h * 64 + j) * 32 + qi) * 64;
#pragma unroll
    for (int dsub = 0; dsub < 4; ++dsub) {
      uint d0, d1;
      asm("v_cvt_pk_bf16_f32 %0, %1, %2" : "=v"(d0) : "v"(oacc[dsub][0]), "v"(oacc[dsub][1]));
      asm("v_cvt_pk_bf16_f32 %0, %1, %2" : "=v"(d1) : "v"(oacc[dsub][2]), "v"(oacc[dsub][3]));
      uint2 dd; dd.x = d0; dd.y = d1;
      *(uint2*)(base + dsub * 16 + 4 * g) = dd;
    }
    if (g == 0) pmd[(h * 64 + j) * 32 + qi] = make_float2(m_run, den);
  } else {
    float inv = 1.f / den;
#pragma unroll
    for (int dsub = 0; dsub < 4; ++dsub)
#pragma unroll
      for (int r = 0; r < 4; ++r)
        Plds[w][lq * 72 + dsub * 16 + 4 * g + r] = f2bf(oacc[dsub][r] * inv);
#pragma unroll
    for (int j = 0; j < 2; ++j) {
      int idx = l + 64 * j;
      int q = idx >> 3, seg = idx & 7;
      uint4 val = *(const uint4*)&Plds[w][q * 72 + seg * 8];
      *(uint4*)(O + (size_t)(q0w + q) * DMODEL + h * HDIM + seg * 8) = val;
    }
  }
}

// ---------------- combine the two key-slices for q rows 1024..2047 ----------------
__global__ __launch_bounds__(256) void attn_combine(
    const ushort* __restrict__ po, const float2* __restrict__ pmd,
    ushort* __restrict__ O)
{
  int idx = blockIdx.x * 256 + threadIdx.x;  // 131072 threads
  int d8 = idx & 7;
  int h = (idx >> 3) & 15;
  int r = idx >> 7;            // 0..1023
  int rb2 = r >> 5, qi = r & 31;
  int j0 = rb2 * 2, j1 = j0 + 1;
  float2 md0 = pmd[(h * 64 + j0) * 32 + qi];
  float2 md1 = pmd[(h * 64 + j1) * 32 + qi];
  float m = fmaxf(md0.x, md1.x);
  float w0 = exp2f((md0.x - m) * C2);
  float w1 = exp2f((md1.x - m) * C2);
  float inv = 1.f / (md0.y * w0 + md1.y * w1);
  const ushort* p0 = po + ((size_t)(h * 64 + j0) * 32 + qi) * 64 + d8 * 8;
  const ushort* p1 = po + ((size_t)(h * 64 + j1) * 32 + qi) * 64 + d8 * 8;
  uint4 a = *(const uint4*)p0, b = *(const uint4*)p1;
  const ushort* ap = (const ushort*)&a;
  const ushort* bp = (const ushort*)&b;
  ushort out8[8];
#pragma unroll
  for (int e = 0; e < 8; ++e)
    out8[e] = f2bf((bf2f(ap[e]) * w0 + bf2f(bp[e]) * w1) * inv);
  int q = 1024 + r;
  *(uint4*)(O + (size_t)q * DMODEL + h * HDIM + d8 * 8) = *(const uint4*)out8;
}

// ---------------- launch ----------------
extern "C" void kernel_launch(void* const* d_in, const int* in_sizes, int n_in,
                              void* d_out, int out_size, void* d_ws, size_t ws_size,
                              hipStream_t stream) {
  const float* x     = (const float*)d_in[0];
  const float* w_in  = (const float*)d_in[1];
  const float* w_out = (const float*)d_in[2];
  const int* icausal = (const int*)d_in[3];

  char* ws = (char*)d_ws;
  ushort* xbf    = (ushort*)(ws);                  // 2048*1024 (vt reuses)
  ushort* winbf  = (ushort*)(ws + 4194304);        // 3072*1024 (partials reuse)
  ushort* woutbf = (ushort*)(ws + 10485760);       // 1024*1024
  ushort* qkv    = (ushort*)(ws + 12582912);       // 2048*3072
  ushort* obuf   = (ushort*)(ws + 25165824);       // 2048*1024
  ushort* vt     = xbf;                            // 16*64*2048 = 4MB
  ushort* po     = winbf;                          // partial O: 4MB (dead winbf)
  float2* pmd    = (float2*)(ws + 4194304 + 4194304);  // 256KB, still in winbf region

  cvt_all<<<6144, 256, 0, stream>>>(x, w_in, w_out, xbf, winbf, woutbf);

  gemm_abt<128, 64, 1><<<16 * 48, 256, 0, stream>>>(xbf, winbf, (void*)qkv, 2048, 3072, 1024);
  rope_kernel<<<8192, 256, 0, stream>>>(qkv);
  transpose_v<<<512, 256, 0, stream>>>(qkv, vt);
  attn_mfma<<<1536, 128, 0, stream>>>(qkv, vt, obuf, po, pmd, icausal);
  attn_combine<<<512, 256, 0, stream>>>(po, pmd, obuf);
  gemm_abt<64, 64, 0><<<32 * 16, 256, 0, stream>>>(obuf, woutbf, d_out, 2048, 1024, 1024);
}

// Round 5
// 101.047 us; speedup vs baseline: 5.5780x; 1.0955x over previous
//
#include <hip/hip_runtime.h>
#include <stdint.h>

#define S_LEN 2048
#define DMODEL 1024
#define NHEAD 16
#define HDIM 64
#define NE 3072
#define C2 0.18033688011112042f  // 0.125 * log2(e)

typedef __attribute__((ext_vector_type(8))) short short8_t;
typedef __attribute__((ext_vector_type(4))) float f32x4;

__device__ __forceinline__ float bf2f(ushort u) {
  union { float f; uint32_t i; } c; c.i = ((uint32_t)u) << 16; return c.f;
}
__device__ __forceinline__ ushort f2bf(float f) {
  union { float f; uint32_t i; } c; c.f = f;
  uint32_t x = c.i;
  return (ushort)((x + 0x7fffu + ((x >> 16) & 1u)) >> 16);
}

__device__ __forceinline__ void gload_lds16(const ushort* g, ushort* l) {
  __builtin_amdgcn_global_load_lds(
      (const __attribute__((address_space(1))) void*)g,
      (__attribute__((address_space(3))) void*)l, 16, 0, 0);
}

// ---------------- fused fp32 -> bf16 convert (x, w_in, w_out) ----------------
__global__ void cvt_all(const float* __restrict__ x, const float* __restrict__ w_in,
                        const float* __restrict__ w_out,
                        ushort* __restrict__ xbf, ushort* __restrict__ winbf,
                        ushort* __restrict__ woutbf) {
  int i = blockIdx.x * blockDim.x + threadIdx.x;
  const float* src; ushort* dst; int off;
  if (i < 524288)       { src = x;     dst = xbf;    off = i; }
  else if (i < 1310720) { src = w_in;  dst = winbf;  off = i - 524288; }
  else                  { src = w_out; dst = woutbf; off = i - 1310720; }
  float4 v = ((const float4*)src)[off];
  ushort4 o;
  o.x = f2bf(v.x); o.y = f2bf(v.y); o.z = f2bf(v.z); o.w = f2bf(v.w);
  ((ushort4*)dst)[off] = o;
}

// ---------------- bf16 GEMM: C[M][N] = A[M][K] * B[N][K]^T ----------------
template<int BM, int BN, int OUT_BF16>
__global__ __launch_bounds__(256) void gemm_abt(
    const ushort* __restrict__ A, const ushort* __restrict__ B,
    void* __restrict__ Cv, int M, int N, int K)
{
  constexpr int AR = BM / 32;
  constexpr int AC = BN / 32;
  constexpr int NG = (BM + BN) / 16;
  constexpr int PG = NG / 4;
  __shared__ ushort lds[(BM + BN) * 32];

  const int nbn = N / BN;
  const int bm = blockIdx.x / nbn;
  const int bn = blockIdx.x - bm * nbn;
  const int tid = threadIdx.x;
  const int w = tid >> 6, l = tid & 63;
  const int wm = w >> 1, wn = w & 1;
  const int fr = l & 15, fg = l >> 4;

  f32x4 acc[AR][AC];
#pragma unroll
  for (int r = 0; r < AR; ++r)
#pragma unroll
    for (int c = 0; c < AC; ++c) acc[r][c] = (f32x4){0.f, 0.f, 0.f, 0.f};

  const ushort* gsrc[PG];
  ushort* ldst[PG];
#pragma unroll
  for (int i = 0; i < PG; ++i) {
    int c = w + 4 * i;
    if (c < BM / 16) {
      gsrc[i] = A + (size_t)(bm * BM + c * 16 + (l >> 2)) * K + (l & 3) * 8;
      ldst[i] = &lds[c * 512];
    } else {
      int c2 = c - BM / 16;
      gsrc[i] = B + (size_t)(bn * BN + c2 * 16 + (l >> 2)) * K + (l & 3) * 8;
      ldst[i] = &lds[BM * 32 + c2 * 512];
    }
  }

  const ushort* fa = &lds[(wm * (BM / 2) + fr) * 32 + fg * 8];
  const ushort* fb = &lds[BM * 32 + (wn * (BN / 2) + fr) * 32 + fg * 8];

  for (int k0 = 0; k0 < K; k0 += 32) {
    __syncthreads();
#pragma unroll
    for (int i = 0; i < PG; ++i) gload_lds16(gsrc[i] + k0, ldst[i]);
    __syncthreads();

    short8_t af[AR], bfr[AC];
#pragma unroll
    for (int r = 0; r < AR; ++r) {
      union { short8_t v; uint4 q; } u;
      u.q = *(const uint4*)(fa + r * 512);
      af[r] = u.v;
    }
#pragma unroll
    for (int c = 0; c < AC; ++c) {
      union { short8_t v; uint4 q; } u;
      u.q = *(const uint4*)(fb + c * 512);
      bfr[c] = u.v;
    }
    __builtin_amdgcn_s_setprio(1);
#pragma unroll
    for (int r = 0; r < AR; ++r)
#pragma unroll
      for (int c = 0; c < AC; ++c)
        acc[r][c] = __builtin_amdgcn_mfma_f32_16x16x32_bf16(af[r], bfr[c], acc[r][c], 0, 0, 0);
    __builtin_amdgcn_s_setprio(0);
  }

  const int row0 = bm * BM + wm * (BM / 2) + fg * 4;
  const int col0 = bn * BN + wn * (BN / 2) + fr;
#pragma unroll
  for (int r = 0; r < AR; ++r)
#pragma unroll
    for (int c = 0; c < AC; ++c)
#pragma unroll
      for (int j = 0; j < 4; ++j) {
        int row = row0 + r * 16 + j;
        int col = col0 + c * 16;
        if (OUT_BF16)
          ((ushort*)Cv)[(size_t)row * N + col] = f2bf(acc[r][c][j]);
        else
          ((float*)Cv)[(size_t)row * N + col] = acc[r][c][j];
      }
}

// ---------------- RoPE in-place on Q and K sections of qkv ----------------
__global__ void rope_kernel(ushort* __restrict__ qkv) {
  int idx = blockIdx.x * blockDim.x + threadIdx.x;
  int i = idx & 31;
  int hh = (idx >> 5) & (NHEAD - 1);
  int sec = (idx >> 9) & 1;
  int srow = idx >> 10;
  float invf = exp2f((float)i * (-13.287712379549449f / 32.f));
  float ang = (float)srow * invf;
  float sn, c;
  sincosf(ang, &sn, &c);
  size_t base = (size_t)srow * NE + (size_t)sec * DMODEL + hh * HDIM;
  float x1 = bf2f(qkv[base + i]);
  float x2 = bf2f(qkv[base + i + 32]);
  qkv[base + i]      = f2bf(x1 * c - x2 * sn);
  qkv[base + i + 32] = f2bf(x2 * c + x1 * sn);
}

// ---------------- V transpose: qkv V-section -> vt[h][d][key] ----------------
__global__ __launch_bounds__(256) void transpose_v(
    const ushort* __restrict__ qkv, ushort* __restrict__ vt)
{
  __shared__ ushort t[64][72];
  const int h = blockIdx.x & 15, c = blockIdx.x >> 4;
  const int tid = threadIdx.x;
#pragma unroll
  for (int j = 0; j < 2; ++j) {
    int idx = tid + 256 * j;
    int key = idx >> 3, d8 = (idx & 7) << 3;
    uint4 v = *(const uint4*)(qkv + (size_t)(c * 64 + key) * NE + 2 * DMODEL + h * HDIM + d8);
    *(uint4*)&t[key][d8] = v;
  }
  __syncthreads();
#pragma unroll
  for (int j = 0; j < 2; ++j) {
    int idx = tid + 256 * j;
    int d = idx >> 3, k8 = (idx & 7) << 3;
    ushort tmp[8];
#pragma unroll
    for (int i = 0; i < 8; ++i) tmp[i] = t[k8 + i][d];
    *(uint4*)(vt + (size_t)(h * 64 + d) * S_LEN + c * 64 + k8) = *(const uint4*)tmp;
  }
}

// ---------------- MFMA flash attention, 4 waves / 64 q-rows per block ----------------
// 896 blocks = 56 items x 16 heads. rb4 in [0,32) = 64-row q-tile.
// ns(rb4) = 1 (rb4<16), 2 (16..23), 3 (24..31) key-slices.
__global__ __launch_bounds__(256, 4) void attn_mfma(
    const ushort* __restrict__ qkv, const ushort* __restrict__ vt,
    ushort* __restrict__ O, ushort* __restrict__ po, float2* __restrict__ pmd,
    const int* __restrict__ icausal)
{
  __shared__ __align__(16) ushort SMEM[20480];  // 40960 B exactly
  ushort* const K0 = SMEM;                      // [2][4096]
  ushort* const V0 = SMEM + 8192;               // [2][4096]
  ushort* const P0 = SMEM + 16384;              // [4096] stride-64 + XOR swizzle

  const int h = blockIdx.x & 15;
  const int i = blockIdx.x >> 4;
  const int j = (i < 8) ? (15 - i) : (i < 48) ? (63 - i) : (55 - i);  // longest-ish first
  int rb4, ns, s;
  if (j < 16)      { rb4 = j; ns = 1; s = 0; }
  else if (j < 32) { rb4 = 16 + ((j - 16) >> 1); ns = 2; s = (j - 16) & 1; }
  else             { int jj = j - 32; int q3 = jj / 3; rb4 = 24 + q3; ns = 3; s = jj - q3 * 3; }

  const int causal = *icausal;
  const int nt = causal ? (rb4 + 1) : (S_LEN / 64);
  const int t0 = s * nt / ns, t1 = (s + 1) * nt / ns;

  const int tid = threadIdx.x;
  const int w = tid >> 6, l = tid & 63;
  const int lq = l & 15, g = l >> 4;
  const int q0w = rb4 * 64 + w * 16;
  const int xsw = (lq & 7) << 4;

  // Q B-fragments
  short8_t qf[2];
  {
    const ushort* qp = qkv + (size_t)(q0w + lq) * NE + h * HDIM;
    union { short8_t v; uint4 q; } u0, u1;
    u0.q = *(const uint4*)(qp + 8 * g);
    u1.q = *(const uint4*)(qp + 32 + 8 * g);
    qf[0] = u0.v; qf[1] = u1.v;
  }

  // staging pointers (advance by constants per tile)
  const int r0 = tid >> 3;
  const int cb = (tid & 7) ^ (r0 & 7);
  const ushort* ksrc = qkv + (size_t)(t0 * 64 + r0) * NE + DMODEL + h * HDIM + cb * 8;
  const ushort* vsrc = vt + (size_t)(h * 64 + r0) * S_LEN + t0 * 64 + cb * 8;

  auto stage = [&](int b) {
    gload_lds16(ksrc,              K0 + b * 4096 + tid * 8);
    gload_lds16(ksrc + 32 * NE,    K0 + b * 4096 + 2048 + tid * 8);
    gload_lds16(vsrc,              V0 + b * 4096 + tid * 8);
    gload_lds16(vsrc + 32 * S_LEN, V0 + b * 4096 + 2048 + tid * 8);
    ksrc += 64 * NE; vsrc += 64;
  };

  float m_run = -1e30f, den = 0.f;
  f32x4 oacc[4];
#pragma unroll
  for (int k = 0; k < 4; ++k) oacc[k] = (f32x4){0.f, 0.f, 0.f, 0.f};

  stage(0);
  __syncthreads();
  int buf = 0;
  char* const Pb = (char*)P0 + w * 2048;

  for (int t = t0; t < t1; ++t) {
    const int k0 = t * 64;
    if (t + 1 < t1) stage(buf ^ 1);

    const char* Kb = (const char*)(K0 + buf * 4096);
    f32x4 sacc[4];
#pragma unroll
    for (int st = 0; st < 4; ++st) sacc[st] = (f32x4){0.f, 0.f, 0.f, 0.f};
    __builtin_amdgcn_s_setprio(1);
#pragma unroll
    for (int dh = 0; dh < 2; ++dh)
#pragma unroll
      for (int st = 0; st < 4; ++st) {
        int off = ((st * 16 + lq) * 128 + (dh * 32 + 8 * g) * 2) ^ xsw;
        union { short8_t v; uint4 q; } u;
        u.q = *(const uint4*)(Kb + off);
        sacc[st] = __builtin_amdgcn_mfma_f32_16x16x32_bf16(u.v, qf[dh], sacc[st], 0, 0, 0);
      }
    __builtin_amdgcn_s_setprio(0);

    // mask + row max (in place)
    float vmax = -3e38f;
    const bool domask = causal && (t == rb4);
#pragma unroll
    for (int st = 0; st < 4; ++st)
#pragma unroll
      for (int r = 0; r < 4; ++r) {
        float sv = sacc[st][r];
        if (domask && (k0 + st * 16 + 4 * g + r > q0w + lq)) sv = -3e38f;
        sacc[st][r] = sv;
        vmax = fmaxf(vmax, sv);
      }
    vmax = fmaxf(vmax, __shfl_xor(vmax, 16));
    vmax = fmaxf(vmax, __shfl_xor(vmax, 32));

    // defer-rescale (T13): only rescale when max grows materially
    if (__any(vmax > m_run + 44.3614196f)) {   // 8 / C2
      float mn = fmaxf(m_run, vmax);
      float alpha = exp2f((m_run - mn) * C2);
      den *= alpha;
#pragma unroll
      for (int k = 0; k < 4; ++k) {
        oacc[k][0] *= alpha; oacc[k][1] *= alpha;
        oacc[k][2] *= alpha; oacc[k][3] *= alpha;
      }
      m_run = mn;
    }
    float mc2 = m_run * C2;
    float psum = 0.f;
#pragma unroll
    for (int st = 0; st < 4; ++st)
#pragma unroll
      for (int r = 0; r < 4; ++r) {
        float p = exp2f(fmaf(sacc[st][r], C2, -mc2));
        psum += p;
        sacc[st][r] = p;
      }
#pragma unroll
    for (int st = 0; st < 4; ++st) {
      uint d0, d1;
      asm("v_cvt_pk_bf16_f32 %0, %1, %2" : "=v"(d0) : "v"(sacc[st][0]), "v"(sacc[st][1]));
      asm("v_cvt_pk_bf16_f32 %0, %1, %2" : "=v"(d1) : "v"(sacc[st][2]), "v"(sacc[st][3]));
      uint2 dd; dd.x = d0; dd.y = d1;
      *(uint2*)(Pb + ((lq * 128 + (st * 16 + 4 * g) * 2) ^ xsw)) = dd;
    }
    psum += __shfl_xor(psum, 16);
    psum += __shfl_xor(psum, 32);
    den += psum;

    const char* Vb = (const char*)(V0 + buf * 4096);
    __builtin_amdgcn_s_setprio(1);
#pragma unroll
    for (int kk = 0; kk < 2; ++kk) {
      union { short8_t v; uint4 q; } pu;
      pu.q = *(const uint4*)(Pb + ((lq * 128 + (kk * 32 + 8 * g) * 2) ^ xsw));
#pragma unroll
      for (int dsub = 0; dsub < 4; ++dsub) {
        int off = (((dsub * 16 + lq) * 128 + (kk * 32 + 8 * g) * 2)) ^ xsw;
        union { short8_t v; uint4 q; } vu;
        vu.q = *(const uint4*)(Vb + off);
        oacc[dsub] = __builtin_amdgcn_mfma_f32_16x16x32_bf16(vu.v, pu.v, oacc[dsub], 0, 0, 0);
      }
    }
    __builtin_amdgcn_s_setprio(0);

    __syncthreads();
    buf ^= 1;
  }

  if (ns > 1) {
    // partial: po[h][slot][qi][d] bf16 (unnormalized), pmd = {m, den}
    const int slot = (rb4 < 24) ? ((rb4 - 16) * 2 + s) : (16 + (rb4 - 24) * 3 + s);
    const int qi = w * 16 + lq;
    ushort* base = po + ((size_t)(h * 40 + slot) * 64 + qi) * 64;
#pragma unroll
    for (int dsub = 0; dsub < 4; ++dsub) {
      uint d0, d1;
      asm("v_cvt_pk_bf16_f32 %0, %1, %2" : "=v"(d0) : "v"(oacc[dsub][0]), "v"(oacc[dsub][1]));
      asm("v_cvt_pk_bf16_f32 %0, %1, %2" : "=v"(d1) : "v"(oacc[dsub][2]), "v"(oacc[dsub][3]));
      uint2 dd; dd.x = d0; dd.y = d1;
      *(uint2*)(base + dsub * 16 + 4 * g) = dd;
    }
    if (g == 0) pmd[(h * 40 + slot) * 64 + qi] = make_float2(m_run, den);
  } else {
    float inv = 1.f / den;
#pragma unroll
    for (int dsub = 0; dsub < 4; ++dsub)
#pragma unroll
      for (int r = 0; r < 4; ++r) {
        int d = dsub * 16 + 4 * g + r;
        *(ushort*)(Pb + ((lq * 128 + d * 2) ^ xsw)) = f2bf(oacc[dsub][r] * inv);
      }
#pragma unroll
    for (int jj = 0; jj < 2; ++jj) {
      int idx = l + 64 * jj;
      int q = idx >> 3, seg = idx & 7;
      uint4 val = *(const uint4*)(Pb + ((q * 128 + seg * 16) ^ ((q & 7) << 4)));
      *(uint4*)(O + (size_t)(q0w - w * 16 + w * 16 + q) * DMODEL + h * HDIM + seg * 8) = val;
    }
  }
}

// ---------------- combine key-slices for q rows 1024..2047 ----------------
__global__ __launch_bounds__(256) void attn_combine(
    const ushort* __restrict__ po, const float2* __restrict__ pmd,
    ushort* __restrict__ O)
{
  int idx = blockIdx.x * 256 + threadIdx.x;  // 131072
  int d8 = idx & 7;
  int h = (idx >> 3) & 15;
  int r = idx >> 7;                // 0..1023
  int rb4 = 16 + (r >> 6), qi = r & 63;
  int base, ns;
  if (rb4 < 24) { base = (rb4 - 16) * 2; ns = 2; }
  else          { base = 16 + (rb4 - 24) * 3; ns = 3; }

  float2 md0 = pmd[(h * 40 + base + 0) * 64 + qi];
  float2 md1 = pmd[(h * 40 + base + 1) * 64 + qi];
  int i2 = (ns == 3) ? 2 : 0;
  float2 md2 = pmd[(h * 40 + base + i2) * 64 + qi];
  float m = fmaxf(fmaxf(md0.x, md1.x), (ns == 3) ? md2.x : -3e38f);
  float w0 = exp2f((md0.x - m) * C2);
  float w1 = exp2f((md1.x - m) * C2);
  float w2 = (ns == 3) ? exp2f((md2.x - m) * C2) : 0.f;
  float inv = 1.f / (md0.y * w0 + md1.y * w1 + md2.y * w2);

  const ushort* p0 = po + ((size_t)(h * 40 + base + 0) * 64 + qi) * 64 + d8 * 8;
  const ushort* p1 = po + ((size_t)(h * 40 + base + 1) * 64 + qi) * 64 + d8 * 8;
  const ushort* p2 = po + ((size_t)(h * 40 + base + i2) * 64 + qi) * 64 + d8 * 8;
  uint4 a = *(const uint4*)p0, b = *(const uint4*)p1, c = *(const uint4*)p2;
  const ushort* ap = (const ushort*)&a;
  const ushort* bp = (const ushort*)&b;
  const ushort* cp = (const ushort*)&c;
  ushort out8[8];
#pragma unroll
  for (int e = 0; e < 8; ++e)
    out8[e] = f2bf((bf2f(ap[e]) * w0 + bf2f(bp[e]) * w1 + bf2f(cp[e]) * w2) * inv);
  int q = rb4 * 64 + qi;
  *(uint4*)(O + (size_t)q * DMODEL + h * HDIM + d8 * 8) = *(const uint4*)out8;
}

// ---------------- launch ----------------
extern "C" void kernel_launch(void* const* d_in, const int* in_sizes, int n_in,
                              void* d_out, int out_size, void* d_ws, size_t ws_size,
                              hipStream_t stream) {
  const float* x     = (const float*)d_in[0];
  const float* w_in  = (const float*)d_in[1];
  const float* w_out = (const float*)d_in[2];
  const int* icausal = (const int*)d_in[3];

  char* ws = (char*)d_ws;
  ushort* xbf    = (ushort*)(ws);                  // 4MB (vt reuses)
  ushort* winbf  = (ushort*)(ws + 4194304);        // 6MB (po/pmd reuse)
  ushort* woutbf = (ushort*)(ws + 10485760);       // 2MB
  ushort* qkv    = (ushort*)(ws + 12582912);       // 12MB
  ushort* obuf   = (ushort*)(ws + 25165824);       // 4MB
  ushort* vt     = xbf;                            // 16*64*2048*2B = 4MB
  ushort* po     = winbf;                          // 16*40*64*64*2B = 5.24MB
  float2* pmd    = (float2*)(ws + 4194304 + 5242880);  // 327KB (within winbf 6MB)

  cvt_all<<<6144, 256, 0, stream>>>(x, w_in, w_out, xbf, winbf, woutbf);

  gemm_abt<128, 64, 1><<<16 * 48, 256, 0, stream>>>(xbf, winbf, (void*)qkv, 2048, 3072, 1024);
  rope_kernel<<<8192, 256, 0, stream>>>(qkv);
  transpose_v<<<512, 256, 0, stream>>>(qkv, vt);
  attn_mfma<<<896, 256, 0, stream>>>(qkv, vt, obuf, po, pmd, icausal);
  attn_combine<<<512, 256, 0, stream>>>(po, pmd, obuf);
  gemm_abt<128, 64, 0><<<16 * 16, 256, 0, stream>>>(obuf, woutbf, d_out, 2048, 1024, 1024);
}